// Round 6
// baseline (456.449 us; speedup 1.0000x reference)
//
#include <hip/hip_runtime.h>
#include <math.h>

#define NBLK 512
#define NTHR 256
#define INV_SQRT_D 0.04419417382415922f

// ws float offsets
#define O_POS   0         // 121*18
#define O_KVXV  2178      // 1024 (v-half of kv_x GEMV)
#define O_QV    3202      // 1024
#define O_W     4226      // 2*25
#define O_PC    4276      // 2*121
#define O_CFIN  4518      // 512
#define O_C2    5030      // 512
#define O_T1    5542      // 2*512*25
#define O_T2    31142     // 2*512*25
#define O_QC    56742     // 2*512
#define O_T3    57766     // 2*2*512*25
#define O_P     108966    // 2*19*51
#define O_BAR   110912    // 16 uints: [0]=init flag, [1..8]=phase counters

#define MAGIC 0x5ca1ab1eu

__device__ __forceinline__ void gridbar(unsigned* bar, int phase) {
    __syncthreads();
    if (threadIdx.x == 0) {
        __hip_atomic_fetch_add(&bar[1 + phase], 1u, __ATOMIC_ACQ_REL, __HIP_MEMORY_SCOPE_AGENT);
        long long spins = 0;
        while (__hip_atomic_load(&bar[1 + phase], __ATOMIC_ACQUIRE, __HIP_MEMORY_SCOPE_AGENT) < (unsigned)NBLK) {
            if (++spins > 200000000LL) break;   // bounded: no hang, worst case wrong answer
        }
    }
    __syncthreads();
}

// 8-row x 25-col GEMM, K=512, LDS staged. All 256 threads of a block call this.
__device__ void gemm8x25(float* sh, const float* __restrict__ A, int lda,
                         const float* __restrict__ B, float* __restrict__ C) {
    float* Bl = sh;          // 6400
    float* Al = sh + 6400;   // 2048
    int t = threadIdx.x;
    int rl = t / 25, j = t - rl * 25;
    bool act = (t < 200);
    float acc = 0.f;
    for (int c = 0; c < 2; c++) {
        __syncthreads();
        for (int idx = t; idx < 6400; idx += 256) Bl[idx] = B[c * 6400 + idx];
        for (int idx = t; idx < 2048; idx += 256) {
            int rr = idx >> 8, dd = idx & 255;
            Al[idx] = A[rr * lda + c * 256 + dd];
        }
        __syncthreads();
        if (act) {
            const float* al = &Al[rl * 256];
            for (int dd = 0; dd < 256; dd++) acc += al[dd] * Bl[dd * 25 + j];
        }
    }
    if (act) C[rl * 25 + j] = acc;
}

__device__ __forceinline__ float blkmax(float v, volatile float* tmp) {
    for (int o = 32; o; o >>= 1) v = fmaxf(v, __shfl_xor(v, o, 64));
    __syncthreads();
    if ((threadIdx.x & 63) == 0) tmp[threadIdx.x >> 6] = v;
    __syncthreads();
    float r = fmaxf(fmaxf(tmp[0], tmp[1]), fmaxf(tmp[2], tmp[3]));
    __syncthreads();
    return r;
}
__device__ __forceinline__ float blksum(float v, volatile float* tmp) {
    for (int o = 32; o; o >>= 1) v += __shfl_xor(v, o, 64);
    __syncthreads();
    if ((threadIdx.x & 63) == 0) tmp[threadIdx.x >> 6] = v;
    __syncthreads();
    float r = tmp[0] + tmp[1] + tmp[2] + tmp[3];
    __syncthreads();
    return r;
}

__global__ __launch_bounds__(NTHR, 4) void mega(
    const float* __restrict__ obs, const float* __restrict__ b_first,
    const float* __restrict__ W_kvx, const float* __restrict__ b_kvx,
    const float* __restrict__ W_kvb, const float* __restrict__ b_kvb,
    const float* __restrict__ W_q, const float* __restrict__ b_q,
    const float* __restrict__ W_fin, const float* __restrict__ b_fin,
    const float* __restrict__ W_sec, const float* __restrict__ b_sec,
    const float* __restrict__ W0_kp, const float* __restrict__ b0_kp,
    const float* __restrict__ W0_q, const float* __restrict__ b0_q,
    const float* __restrict__ W1_kp, const float* __restrict__ b1_kp,
    const float* __restrict__ W1_q, const float* __restrict__ b1_q,
    float* __restrict__ ws, float* __restrict__ out)
{
    __shared__ float sh[8448];
    unsigned* bar = (unsigned*)(ws + O_BAR);
    int blk = blockIdx.x, t = threadIdx.x, wv = t >> 6, lane = t & 63;

    // ---- barrier init handshake (ws poisoned to 0xAA each launch; 0xAAAAAAAA != MAGIC) ----
    if (blk == 0) {
        if (t < 8) __hip_atomic_store(&bar[1 + t], 0u, __ATOMIC_RELAXED, __HIP_MEMORY_SCOPE_AGENT);
        __syncthreads();
        if (t == 0) __hip_atomic_store(&bar[0], MAGIC, __ATOMIC_RELEASE, __HIP_MEMORY_SCOPE_AGENT);
    } else {
        if (t == 0) {
            long long spins = 0;
            while (__hip_atomic_load(&bar[0], __ATOMIC_ACQUIRE, __HIP_MEMORY_SCOPE_AGENT) != MAGIC)
                if (++spins > 200000000LL) break;
        }
        __syncthreads();
    }

    // ================= P0: pos | T1 = W_fin,h @ Wv_h | kvx_v, qv =================
    if (blk < 128) {
        int h = blk >> 6, chunk = blk & 63, r0 = chunk * 8;
        gemm8x25(sh, W_fin + r0 * 1024 + h * 512, 1024,
                 W_kvb + (1024 + h * 512) * 25, ws + O_T1 + (h * 512 + r0) * 25);
    } else if (blk < 384) {
        for (int k = 0; k < 2; k++) {
            int row = (blk - 128) * 8 + wv * 2 + k;
            const float* R; float bias; int oi;
            if (row < 1024) { R = W_kvx + (1024 + row) * 512; bias = b_kvx[1024 + row]; oi = O_KVXV + row; }
            else { int r2 = row - 1024; R = W_q + r2 * 512; bias = b_q[r2]; oi = O_QV + r2; }
            float a = 0.f;
            for (int d = lane; d < 512; d += 64) a += R[d] * fmaxf(b_first[d], 0.f);
            for (int o = 32; o; o >>= 1) a += __shfl_xor(a, o, 64);
            if (lane == 0) ws[oi] = a + bias;
        }
    } else if (blk < 393) {
        int gid = (blk - 384) * 256 + t;
        if (gid < 2178) {
            int p = gid / 18, jj = gid % 18;
            int i = p / 11, j = p % 11;
            float r = (i - 5) * 0.2f, c = (j - 5) * 0.2f, z = 0.5f * (r + c);
            float xs3[3] = {r, c, z};
            float pp3[3] = {1.f, 2.f, 4.f};
            int sc = jj / 9, rem = jj % 9, a = rem / 3, q = rem % 3;
            float ang = 6.283185307179586f * xs3[q] / pp3[a];
            ws[O_POS + p * 18 + jj] = sc ? sinf(ang) : cosf(ang);
        }
    }
    gridbar(bar, 0);

    // ================= P1: T2 = W_sec @ T1 | w = qv.Wk | cfin =================
    if (blk < 128) {
        int h = blk >> 6, chunk = blk & 63, r0 = chunk * 8;
        gemm8x25(sh, W_sec + r0 * 512, 512,
                 ws + O_T1 + h * 512 * 25, ws + O_T2 + (h * 512 + r0) * 25);
    } else if (blk < 141) {
        int wid = (blk - 128) * 4 + wv;
        if (wid < 50) {
            int h = wid / 25, j = wid % 25;
            float a = 0.f;
            for (int d = lane; d < 512; d += 64) a += W_kvb[(h * 512 + d) * 25 + j] * ws[O_QV + h * 512 + d];
            for (int o = 32; o; o >>= 1) a += __shfl_xor(a, o, 64);
            if (lane == 0) ws[O_W + wid] = a;
        }
    } else if (blk < 269) {
        int row = (blk - 141) * 4 + wv;
        float a = 0.f;
        for (int d = lane; d < 1024; d += 64) a += W_fin[row * 1024 + d] * (ws[O_KVXV + d] + b_kvb[1024 + d]);
        for (int o = 32; o; o >>= 1) a += __shfl_xor(a, o, 64);
        if (lane == 0) ws[O_CFIN + row] = a + b_fin[row];
    }
    gridbar(bar, 1);

    // ================= P2: T3 = Wq_i @ T2 | c2 | pc =================
    if (blk < 256) {
        int i = blk >> 7, h = (blk >> 6) & 1, chunk = blk & 63, r0 = chunk * 8;
        const float* Wq = i ? W1_q : W0_q;
        gemm8x25(sh, Wq + r0 * 512, 512,
                 ws + O_T2 + h * 512 * 25, ws + O_T3 + ((i * 2 + h) * 512 + r0) * 25);
    } else if (blk < 384) {
        int row = (blk - 256) * 4 + wv;
        float a = 0.f;
        for (int d = lane; d < 512; d += 64) a += W_sec[row * 512 + d] * ws[O_CFIN + d];
        for (int o = 32; o; o >>= 1) a += __shfl_xor(a, o, 64);
        if (lane == 0) ws[O_C2 + row] = a + b_sec[row];
    } else if (blk == 384) {
        if (t < 242) {
            int h = t / 121, p = t % 121;
            float a = 0.f;
            for (int j = 0; j < 18; j++) a += ws[O_W + h * 25 + 7 + j] * ws[O_POS + p * 18 + j];
            ws[O_PC + h * 121 + p] = a;
        }
    }
    gridbar(bar, 2);

    // ================= P3: qc | P columns 1..50 = K_i^T @ T3 =================
    if (blk < 256) {
        int row = blk * 4 + wv, i = row >> 9, r = row & 511;
        const float* Wq = i ? W1_q : W0_q;
        const float* bq = i ? b1_q : b0_q;
        float a = 0.f;
        for (int d = lane; d < 512; d += 64) a += Wq[r * 512 + d] * ws[O_C2 + d];
        for (int o = 32; o; o >>= 1) a += __shfl_xor(a, o, 64);
        if (lane == 0) ws[O_QC + row] = a + bq[r];
    } else if (blk < 506) {
        int wid = (blk - 256) * 4 + wv;
        for (int rep = 0; rep < 2; rep++) {
            int D = wid * 2 + rep;
            if (D < 1900) {
                int i = D / 950, rem = D % 950, r = rem / 50, c1 = rem % 50;
                int h = c1 / 25, f = c1 % 25;
                const float* kpW = i ? W1_kp : W0_kp;
                const float* kpb = i ? b1_kp : b0_kp;
                float a = 0.f;
                for (int d = lane; d < 512; d += 64) {
                    float kv = (r == 0) ? kpb[d] : kpW[d * 18 + (r - 1)];
                    a += kv * ws[O_T3 + ((i * 2 + h) * 512 + d) * 25 + f];
                }
                for (int o = 32; o; o >>= 1) a += __shfl_xor(a, o, 64);
                if (lane == 0) ws[O_P + i * 969 + r * 51 + (1 + c1)] = a;
            }
        }
    }
    gridbar(bar, 3);

    // ================= P4: per-batch main (bbar shared across the 2 policies) =================
    {
        float* sgl  = sh;           // 121
        float* nbs  = sh + 128;     // 121*7
        float* att  = sh + 1024;    // 121
        float* bbar = sh + 1152;    // 2*25
        float* colp = sh + 1202;    // 19*8
        float* cvec = sh + 1356;    // 19
        float* tmp  = sh + 1376;    // 4
        int b = blk;
        if (t < 121) sgl[t] = obs[(b * 121 + t) * 2] - obs[(b * 121 + t) * 2 + 1];
        __syncthreads();
        float dots[2];
        if (t < 121) {
            const int DRo[7] = {-1, -1, 0, 0, 0, -1, -1};
            const int DCo[7] = {0, 1, -1, 0, 1, -1, 0};
            int i = t / 11, j = t % 11;
            float nb[7];
            for (int k = 0; k < 7; k++) {
                int ii = i + DRo[k], jj = j + DCo[k];
                float v = (ii >= 0 && ii < 11 && jj >= 0 && jj < 11) ? sgl[ii * 11 + jj] : 0.f;
                nb[k] = v; nbs[t * 7 + k] = v;
            }
            for (int h = 0; h < 2; h++) {
                float acc = ws[O_PC + h * 121 + t];
                for (int k = 0; k < 7; k++) acc += ws[O_W + h * 25 + k] * nb[k];
                dots[h] = acc * INV_SQRT_D;
            }
        } else { dots[0] = dots[1] = -INFINITY; }
        for (int h = 0; h < 2; h++) {
            float m = blkmax(dots[h], tmp);
            float e = (t < 121) ? expf(dots[h] - m) : 0.f;
            float s = blksum(e, tmp);
            if (t < 121) att[t] = e / s;
            __syncthreads();
            if (t < 25) {
                float acc = 0.f;
                if (t < 7) { for (int p = 0; p < 121; p++) acc += att[p] * nbs[p * 7 + t]; }
                else { int j = t - 7; for (int p = 0; p < 121; p++) acc += att[p] * ws[O_POS + p * 18 + j]; }
                bbar[h * 25 + t] = acc;
            }
            __syncthreads();
        }
        for (int pol = 0; pol < 2; pol++) {
            const float* kpW = pol ? W1_kp : W0_kp;
            const float* kpb = pol ? b1_kp : b0_kp;
            if (t < 152) {                       // col0 of P (K_i^T @ qc_i) partials
                int r = t >> 3, sgm = t & 7;
                const float* qcp = ws + O_QC + pol * 512;
                float a = 0.f;
                for (int d = sgm * 64; d < sgm * 64 + 64; d++) {
                    float kv = (r == 0) ? kpb[d] : kpW[d * 18 + (r - 1)];
                    a += kv * qcp[d];
                }
                colp[r * 8 + sgm] = a;
            }
            __syncthreads();
            if (t < 19) {
                float a = 0.f;
                for (int s = 0; s < 8; s++) a += colp[t * 8 + s];
                const float* Pr = ws + O_P + pol * 969 + t * 51;
                for (int c = 1; c < 51; c++) a += Pr[c] * bbar[c - 1];
                cvec[t] = a;
            }
            __syncthreads();
            float d;
            if (t < 121) {
                d = cvec[0];
                for (int j = 0; j < 18; j++) d += ws[O_POS + t * 18 + j] * cvec[1 + j];
                d *= INV_SQRT_D;
            } else d = -INFINITY;
            float m = blkmax(d, tmp);
            float e = (t < 121) ? expf(d - m) : 0.f;
            float s = blksum(e, tmp);
            float ls = logf(s);
            if (t < 121) out[pol * 61952 + b * 121 + t] = d - m - ls;
            __syncthreads();
        }
    }
}

extern "C" void kernel_launch(void* const* d_in, const int* in_sizes, int n_in,
                              void* d_out, int out_size, void* d_ws, size_t ws_size,
                              hipStream_t stream) {
    const float* obs     = (const float*)d_in[0];
    const float* b_first = (const float*)d_in[2];
    const float* W_kvx   = (const float*)d_in[3];
    const float* b_kvx   = (const float*)d_in[4];
    const float* W_kvb   = (const float*)d_in[5];
    const float* b_kvb   = (const float*)d_in[6];
    const float* W_q     = (const float*)d_in[7];
    const float* b_q     = (const float*)d_in[8];
    const float* W_fin   = (const float*)d_in[9];
    const float* b_fin   = (const float*)d_in[10];
    const float* W_sec   = (const float*)d_in[11];
    const float* b_sec   = (const float*)d_in[12];
    const float* W0_kp   = (const float*)d_in[13];
    const float* b0_kp   = (const float*)d_in[14];
    const float* W0_q    = (const float*)d_in[17];
    const float* b0_q    = (const float*)d_in[18];
    const float* W1_kp   = (const float*)d_in[19];
    const float* b1_kp   = (const float*)d_in[20];
    const float* W1_q    = (const float*)d_in[23];
    const float* b1_q    = (const float*)d_in[24];
    float* ws = (float*)d_ws;
    float* out = (float*)d_out;

    hipLaunchKernelGGL(mega, dim3(NBLK), dim3(NTHR), 0, stream,
                       obs, b_first, W_kvx, b_kvx, W_kvb, b_kvb, W_q, b_q,
                       W_fin, b_fin, W_sec, b_sec,
                       W0_kp, b0_kp, W0_q, b0_q, W1_kp, b1_kp, W1_q, b1_q,
                       ws, out);
}

// Round 7
// 265.323 us; speedup vs baseline: 1.7204x; 1.7204x over previous
//
#include <hip/hip_runtime.h>
#include <math.h>

#define NBLK 256
#define NTHR 256
#define INV_SQRT_D 0.04419417382415922f
#define MAGIC 0x5ca1ab1eu
#define SUBS 8
#define SUBCNT (NBLK / SUBS)   // 32

// ws float offsets
#define O_POS   0         // 121*18
#define O_KVXV  2178      // 1024 (v-half of kv_x GEMV)
#define O_QV    3202      // 1024
#define O_W     4226      // 2*25
#define O_PC    4276      // 2*121
#define O_CFIN  4518      // 512
#define O_C2    5030      // 512
#define O_T1    5542      // 2*512*25
#define O_T2    31142     // 2*512*25
#define O_QC    56742     // 2*512
#define O_T3    57766     // 2*2*512*25
#define O_P     108966    // 2*19*51
#define O_BAR   110912    // barrier region (uints): [0]=init flag; per-phase blocks below

// per-phase barrier block: base = 32 + phase*320 (uint idx)
//   sub counter s at +s*32 (s=0..7), root at +256, release flag at +288

__device__ __forceinline__ void gridbar(unsigned* bar, int phase, int blk) {
    __syncthreads();
    if (threadIdx.x == 0) {
        unsigned* ph = bar + 32 + phase * 320;
        unsigned prev = __hip_atomic_fetch_add(&ph[(blk & (SUBS - 1)) * 32], 1u,
                                               __ATOMIC_ACQ_REL, __HIP_MEMORY_SCOPE_AGENT);
        if (prev == SUBCNT - 1) {
            unsigned pr = __hip_atomic_fetch_add(&ph[256], 1u,
                                                 __ATOMIC_ACQ_REL, __HIP_MEMORY_SCOPE_AGENT);
            if (pr == SUBS - 1)
                __hip_atomic_store(&ph[288], MAGIC, __ATOMIC_RELEASE, __HIP_MEMORY_SCOPE_AGENT);
        }
        int spins = 0;
        while (__hip_atomic_load(&ph[288], __ATOMIC_ACQUIRE, __HIP_MEMORY_SCOPE_AGENT) != MAGIC) {
            __builtin_amdgcn_s_sleep(16);          // ~1024 clk between polls
            if (++spins > 500000) break;           // bounded: no hang
        }
    }
    __syncthreads();
}

// 8-row x 25-col GEMM, K=512, LDS staged. All 256 threads participate.
__device__ void gemm8x25(float* sh, const float* __restrict__ A, int lda,
                         const float* __restrict__ B, float* __restrict__ C) {
    float* Bl = sh;          // 6400
    float* Al = sh + 6400;   // 2048
    int t = threadIdx.x;
    int rl = t / 25, j = t - rl * 25;
    bool act = (t < 200);
    float acc = 0.f;
    for (int c = 0; c < 2; c++) {
        __syncthreads();
        for (int idx = t; idx < 6400; idx += 256) Bl[idx] = B[c * 6400 + idx];
        for (int idx = t; idx < 2048; idx += 256) {
            int rr = idx >> 8, dd = idx & 255;
            Al[idx] = A[rr * lda + c * 256 + dd];
        }
        __syncthreads();
        if (act) {
            const float* al = &Al[rl * 256];
            for (int dd = 0; dd < 256; dd++) acc += al[dd] * Bl[dd * 25 + j];
        }
    }
    if (act) C[rl * 25 + j] = acc;
}

__device__ __forceinline__ float blkmax(float v, volatile float* tmp) {
    for (int o = 32; o; o >>= 1) v = fmaxf(v, __shfl_xor(v, o, 64));
    __syncthreads();
    if ((threadIdx.x & 63) == 0) tmp[threadIdx.x >> 6] = v;
    __syncthreads();
    float r = fmaxf(fmaxf(tmp[0], tmp[1]), fmaxf(tmp[2], tmp[3]));
    __syncthreads();
    return r;
}
__device__ __forceinline__ float blksum(float v, volatile float* tmp) {
    for (int o = 32; o; o >>= 1) v += __shfl_xor(v, o, 64);
    __syncthreads();
    if ((threadIdx.x & 63) == 0) tmp[threadIdx.x >> 6] = v;
    __syncthreads();
    float r = tmp[0] + tmp[1] + tmp[2] + tmp[3];
    __syncthreads();
    return r;
}

__global__ __launch_bounds__(NTHR) void mega(
    const float* __restrict__ obs, const float* __restrict__ b_first,
    const float* __restrict__ W_kvx, const float* __restrict__ b_kvx,
    const float* __restrict__ W_kvb, const float* __restrict__ b_kvb,
    const float* __restrict__ W_q, const float* __restrict__ b_q,
    const float* __restrict__ W_fin, const float* __restrict__ b_fin,
    const float* __restrict__ W_sec, const float* __restrict__ b_sec,
    const float* __restrict__ W0_kp, const float* __restrict__ b0_kp,
    const float* __restrict__ W0_q, const float* __restrict__ b0_q,
    const float* __restrict__ W1_kp, const float* __restrict__ b1_kp,
    const float* __restrict__ W1_q, const float* __restrict__ b1_q,
    float* __restrict__ ws, float* __restrict__ out)
{
    __shared__ float sh[8448];
    unsigned* bar = (unsigned*)(ws + O_BAR);
    int blk = blockIdx.x, t = threadIdx.x, wv = t >> 6, lane = t & 63;

    // ---- block 0 publishes barrier init FIRST (others check before gridbar 0) ----
    if (blk == 0) {
        if (t < 36) {   // 4 phases x (8 subs + root)
            int phase = t / 9, item = t % 9;
            unsigned idx = 32u + phase * 320 + (item < 8 ? item * 32 : 256);
            __hip_atomic_store(&bar[idx], 0u, __ATOMIC_RELAXED, __HIP_MEMORY_SCOPE_AGENT);
        }
        __syncthreads();
        if (t == 0) __hip_atomic_store(&bar[0], MAGIC, __ATOMIC_RELEASE, __HIP_MEMORY_SCOPE_AGENT);
    }

    // ================= P0: T1 = W_fin,h @ Wv_h | kvx_v, qv | pos =================
    if (blk < 128) {
        int h = blk >> 6, chunk = blk & 63, r0 = chunk * 8;
        gemm8x25(sh, W_fin + r0 * 1024 + h * 512, 1024,
                 W_kvb + (1024 + h * 512) * 25, ws + O_T1 + (h * 512 + r0) * 25);
    } else {
        for (int k = 0; k < 4; k++) {
            int row = (blk - 128) * 16 + wv * 4 + k;
            const float* R; float bias; int oi;
            if (row < 1024) { R = W_kvx + (1024 + row) * 512; bias = b_kvx[1024 + row]; oi = O_KVXV + row; }
            else { int r2 = row - 1024; R = W_q + r2 * 512; bias = b_q[r2]; oi = O_QV + r2; }
            float a = 0.f;
            for (int d = lane; d < 512; d += 64) a += R[d] * fmaxf(b_first[d], 0.f);
            for (int o = 32; o; o >>= 1) a += __shfl_xor(a, o, 64);
            if (lane == 0) ws[oi] = a + bias;
        }
        if (t < 18) {
            int gid = (blk - 128) * 18 + t;
            if (gid < 2178) {
                int p = gid / 18, jj = gid % 18;
                int i = p / 11, j = p % 11;
                float r = (i - 5) * 0.2f, c = (j - 5) * 0.2f, z = 0.5f * (r + c);
                float xs3[3] = {r, c, z};
                float pp3[3] = {1.f, 2.f, 4.f};
                int sc = jj / 9, rem = jj % 9, a = rem / 3, q = rem % 3;
                float ang = 6.283185307179586f * xs3[q] / pp3[a];
                ws[O_POS + p * 18 + jj] = sc ? sinf(ang) : cosf(ang);
            }
        }
    }
    // wait for barrier init (cheap: block 0 published it long ago)
    if (blk != 0 && t == 0) {
        int spins = 0;
        while (__hip_atomic_load(&bar[0], __ATOMIC_ACQUIRE, __HIP_MEMORY_SCOPE_AGENT) != MAGIC) {
            __builtin_amdgcn_s_sleep(16);
            if (++spins > 500000) break;
        }
    }
    gridbar(bar, 0, blk);

    // ================= P1: T2 = W_sec @ T1 | cfin | w =================
    if (blk < 128) {
        int h = blk >> 6, chunk = blk & 63, r0 = chunk * 8;
        gemm8x25(sh, W_sec + r0 * 512, 512,
                 ws + O_T1 + h * 512 * 25, ws + O_T2 + (h * 512 + r0) * 25);
    } else {
        int row = (blk - 128) * 4 + wv;
        float a = 0.f;
        for (int d = lane; d < 1024; d += 64) a += W_fin[row * 1024 + d] * (ws[O_KVXV + d] + b_kvb[1024 + d]);
        for (int o = 32; o; o >>= 1) a += __shfl_xor(a, o, 64);
        if (lane == 0) ws[O_CFIN + row] = a + b_fin[row];
        if (blk < 141) {
            int wid = (blk - 128) * 4 + wv;
            if (wid < 50) {
                int h = wid / 25, j = wid % 25;
                float b2 = 0.f;
                for (int d = lane; d < 512; d += 64) b2 += W_kvb[(h * 512 + d) * 25 + j] * ws[O_QV + h * 512 + d];
                for (int o = 32; o; o >>= 1) b2 += __shfl_xor(b2, o, 64);
                if (lane == 0) ws[O_W + wid] = b2;
            }
        }
    }
    gridbar(bar, 1, blk);

    // ================= P2: T3 = Wq_i @ T2 (all blocks) | c2 (blk<128 extra) | pc (blk 128) =================
    {
        int i = blk >> 7, h = (blk >> 6) & 1, chunk = blk & 63, r0 = chunk * 8;
        const float* Wq = i ? W1_q : W0_q;
        gemm8x25(sh, Wq + r0 * 512, 512,
                 ws + O_T2 + h * 512 * 25, ws + O_T3 + ((i * 2 + h) * 512 + r0) * 25);
    }
    if (blk < 128) {
        int row = blk * 4 + wv;
        float a = 0.f;
        for (int d = lane; d < 512; d += 64) a += W_sec[row * 512 + d] * ws[O_CFIN + d];
        for (int o = 32; o; o >>= 1) a += __shfl_xor(a, o, 64);
        if (lane == 0) ws[O_C2 + row] = a + b_sec[row];
    } else if (blk == 128) {
        if (t < 242) {
            int h = t / 121, p = t % 121;
            float a = 0.f;
            for (int j = 0; j < 18; j++) a += ws[O_W + h * 25 + 7 + j] * ws[O_POS + p * 18 + j];
            ws[O_PC + h * 121 + p] = a;
        }
    }
    gridbar(bar, 2, blk);

    // ================= P3: qc (all blocks) | P cols 1..50 (all blocks) =================
    {
        int row = blk * 4 + wv, i = row >> 9, r = row & 511;
        const float* Wq = i ? W1_q : W0_q;
        const float* bq = i ? b1_q : b0_q;
        float a = 0.f;
        for (int d = lane; d < 512; d += 64) a += Wq[r * 512 + d] * ws[O_C2 + d];
        for (int o = 32; o; o >>= 1) a += __shfl_xor(a, o, 64);
        if (lane == 0) ws[O_QC + row] = a + bq[r];
    }
    for (int rep = 0; rep < 2; rep++) {
        int D = (blk * 4 + wv) * 2 + rep;
        if (D < 1900) {
            int i = D / 950, rem = D % 950, r = rem / 50, c1 = rem % 50;
            int h = c1 / 25, f = c1 % 25;
            const float* kpW = i ? W1_kp : W0_kp;
            const float* kpb = i ? b1_kp : b0_kp;
            float a = 0.f;
            for (int d = lane; d < 512; d += 64) {
                float kv = (r == 0) ? kpb[d] : kpW[d * 18 + (r - 1)];
                a += kv * ws[O_T3 + ((i * 2 + h) * 512 + d) * 25 + f];
            }
            for (int o = 32; o; o >>= 1) a += __shfl_xor(a, o, 64);
            if (lane == 0) ws[O_P + i * 969 + r * 51 + (1 + c1)] = a;
        }
    }
    gridbar(bar, 3, blk);

    // ================= P4: batch-independent col0, then 2 batches per block =================
    {
        float* sgl  = sh;           // 121
        float* nbs  = sh + 128;     // 847
        float* att  = sh + 1024;    // 121
        float* bbar = sh + 1152;    // 50
        float* cvec = sh + 1216;    // 19
        float* tmp  = sh + 1248;    // 4
        float* colp = sh + 1280;    // 152
        float* col0 = sh + 1440;    // 38

        __syncthreads();
        if (t < 152) {              // col0[pol][r] = sum_d K_i[d][r] * qc_i[d]
            int pol = t / 76, rr = (t % 76) >> 2, sgm = t & 3;
            const float* kpW = pol ? W1_kp : W0_kp;
            const float* kpb = pol ? b1_kp : b0_kp;
            const float* qcp = ws + O_QC + pol * 512;
            float a = 0.f;
            for (int d = sgm * 128; d < sgm * 128 + 128; d++) {
                float kv = (rr == 0) ? kpb[d] : kpW[d * 18 + (rr - 1)];
                a += kv * qcp[d];
            }
            colp[t] = a;
        }
        __syncthreads();
        if (t < 38) {
            int pol = t / 19, rr = t % 19;
            col0[t] = colp[pol * 76 + rr * 4] + colp[pol * 76 + rr * 4 + 1]
                    + colp[pol * 76 + rr * 4 + 2] + colp[pol * 76 + rr * 4 + 3];
        }

        for (int rep2 = 0; rep2 < 2; rep2++) {
            int b = blk + rep2 * 256;
            __syncthreads();
            if (t < 121) sgl[t] = obs[(b * 121 + t) * 2] - obs[(b * 121 + t) * 2 + 1];
            __syncthreads();
            float dots[2];
            if (t < 121) {
                const int DRo[7] = {-1, -1, 0, 0, 0, -1, -1};
                const int DCo[7] = {0, 1, -1, 0, 1, -1, 0};
                int i = t / 11, j = t % 11;
                float nb[7];
                for (int k = 0; k < 7; k++) {
                    int ii = i + DRo[k], jj = j + DCo[k];
                    float v = (ii >= 0 && ii < 11 && jj >= 0 && jj < 11) ? sgl[ii * 11 + jj] : 0.f;
                    nb[k] = v; nbs[t * 7 + k] = v;
                }
                for (int h = 0; h < 2; h++) {
                    float acc = ws[O_PC + h * 121 + t];
                    for (int k = 0; k < 7; k++) acc += ws[O_W + h * 25 + k] * nb[k];
                    dots[h] = acc * INV_SQRT_D;
                }
            } else { dots[0] = dots[1] = -INFINITY; }
            for (int h = 0; h < 2; h++) {
                float m = blkmax(dots[h], tmp);
                float e = (t < 121) ? expf(dots[h] - m) : 0.f;
                float s = blksum(e, tmp);
                if (t < 121) att[t] = e / s;
                __syncthreads();
                if (t < 25) {
                    float acc = 0.f;
                    if (t < 7) { for (int p = 0; p < 121; p++) acc += att[p] * nbs[p * 7 + t]; }
                    else { int j = t - 7; for (int p = 0; p < 121; p++) acc += att[p] * ws[O_POS + p * 18 + j]; }
                    bbar[h * 25 + t] = acc;
                }
                __syncthreads();
            }
            for (int pol = 0; pol < 2; pol++) {
                if (t < 19) {
                    float a = col0[pol * 19 + t];
                    const float* Pr = ws + O_P + pol * 969 + t * 51;
                    for (int c = 1; c < 51; c++) a += Pr[c] * bbar[c - 1];
                    cvec[t] = a;
                }
                __syncthreads();
                float d;
                if (t < 121) {
                    d = cvec[0];
                    for (int j = 0; j < 18; j++) d += ws[O_POS + t * 18 + j] * cvec[1 + j];
                    d *= INV_SQRT_D;
                } else d = -INFINITY;
                float m = blkmax(d, tmp);
                float e = (t < 121) ? expf(d - m) : 0.f;
                float s = blksum(e, tmp);
                float ls = logf(s);
                if (t < 121) out[pol * 61952 + b * 121 + t] = d - m - ls;
                __syncthreads();
            }
        }
    }
}

extern "C" void kernel_launch(void* const* d_in, const int* in_sizes, int n_in,
                              void* d_out, int out_size, void* d_ws, size_t ws_size,
                              hipStream_t stream) {
    const float* obs     = (const float*)d_in[0];
    const float* b_first = (const float*)d_in[2];
    const float* W_kvx   = (const float*)d_in[3];
    const float* b_kvx   = (const float*)d_in[4];
    const float* W_kvb   = (const float*)d_in[5];
    const float* b_kvb   = (const float*)d_in[6];
    const float* W_q     = (const float*)d_in[7];
    const float* b_q     = (const float*)d_in[8];
    const float* W_fin   = (const float*)d_in[9];
    const float* b_fin   = (const float*)d_in[10];
    const float* W_sec   = (const float*)d_in[11];
    const float* b_sec   = (const float*)d_in[12];
    const float* W0_kp   = (const float*)d_in[13];
    const float* b0_kp   = (const float*)d_in[14];
    const float* W0_q    = (const float*)d_in[17];
    const float* b0_q    = (const float*)d_in[18];
    const float* W1_kp   = (const float*)d_in[19];
    const float* b1_kp   = (const float*)d_in[20];
    const float* W1_q    = (const float*)d_in[23];
    const float* b1_q    = (const float*)d_in[24];
    float* ws = (float*)d_ws;
    float* out = (float*)d_out;

    hipLaunchKernelGGL(mega, dim3(NBLK), dim3(NTHR), 0, stream,
                       obs, b_first, W_kvx, b_kvx, W_kvb, b_kvb, W_q, b_q,
                       W_fin, b_fin, W_sec, b_sec,
                       W0_kp, b0_kp, W0_q, b0_q, W1_kp, b1_kp, W1_q, b1_q,
                       ws, out);
}